// Round 2
// baseline (212.010 us; speedup 1.0000x reference)
//
#include <hip/hip_runtime.h>
#include <hip/hip_bf16.h>
#include <cstdint>

#define NN 8192
#define DD 512

typedef unsigned short u16;
typedef __attribute__((ext_vector_type(8))) short short8;
typedef __attribute__((ext_vector_type(4))) float f32x4;

// workspace layout (bytes)
#define FB_OFF   ((size_t)0)                      // bf16 features: NN*DD*2 = 8 MB
#define SQ_OFF   (FB_OFF + (size_t)NN*DD*2)       // fp32 sq norms: NN*4
#define ND_OFF   (SQ_OFF + (size_t)NN*4)          // fp32 neg_dist: NN*4
#define ACC_OFF  (ND_OFF + (size_t)NN*4)          // total(float) @+0, cnt(int) @+4
#define CC_OFF   (ACC_OFF + 64)                   // class histogram: 256*4

// ---------------- K1: sq norms, bf16 cast, class histogram ----------------
__global__ __launch_bounds__(256) void k_prep(const float* __restrict__ F,
    const int* __restrict__ labels,
    u16* __restrict__ Fb, float* __restrict__ sq, int* __restrict__ cc) {
  const int wid = threadIdx.x >> 6, lane = threadIdx.x & 63;
  const int row = blockIdx.x * 4 + wid;
  const float* fr = F + (size_t)row * DD + lane * 8;
  float4 v0 = *(const float4*)fr;
  float4 v1 = *(const float4*)(fr + 4);
  float s = v0.x*v0.x + v0.y*v0.y + v0.z*v0.z + v0.w*v0.w
          + v1.x*v1.x + v1.y*v1.y + v1.z*v1.z + v1.w*v1.w;
  #pragma unroll
  for (int o = 32; o; o >>= 1) s += __shfl_xor(s, o);
  float t[8] = {v0.x, v0.y, v0.z, v0.w, v1.x, v1.y, v1.z, v1.w};
  unsigned p[8];
  #pragma unroll
  for (int e = 0; e < 8; ++e) {   // RNE fp32->bf16
    unsigned b = __float_as_uint(t[e]);
    b += 0x7fffu + ((b >> 16) & 1u);
    p[e] = b >> 16;
  }
  uint4 w;
  w.x = p[0] | (p[1] << 16); w.y = p[2] | (p[3] << 16);
  w.z = p[4] | (p[5] << 16); w.w = p[6] | (p[7] << 16);
  *(uint4*)(Fb + (size_t)row * DD + lane * 8) = w;
  if (lane == 0) {
    sq[row] = s;
    atomicAdd(&cc[labels[row] & 255], 1);
  }
}

// -------- K2: k-th negative (ballot scan) + fp32 neg_dist + valid count ---
__global__ __launch_bounds__(256) void k_neg(const float* __restrict__ F,
    const float* __restrict__ sq, const int* __restrict__ labels,
    const float* __restrict__ negu, const int* __restrict__ cc,
    float* __restrict__ nd, int* __restrict__ cnt) {
  const int wid = threadIdx.x >> 6, lane = threadIdx.x & 63;
  const int i = blockIdx.x * 4 + wid;
  const int c = labels[i];
  const int nc = cc[c & 255];
  const int n_neg = NN - nc;
  if (n_neg <= 0) { if (lane == 0) nd[i] = __builtin_inff(); return; }
  int k = (int)floorf(negu[i] * (float)n_neg);   // exact fp32 replica of reference
  k = k < 0 ? 0 : (k > n_neg - 1 ? n_neg - 1 : k);
  int j = 0, running = 0;
  for (int base = 0; base < NN; base += 64) {
    const int lb = labels[base + lane];
    const unsigned long long m = __ballot(lb != c);
    const int pc = __popcll(m);
    if (running + pc > k) {
      const int need = k - running;
      const unsigned long long below = m & ((1ull << lane) - 1ull);
      const bool mine = ((m >> lane) & 1ull) && (__popcll(below) == need);
      const unsigned long long sel = __ballot(mine);
      j = base + __builtin_ctzll(sel);
      break;
    }
    running += pc;
  }
  // fp32 dot(f_i, f_j)
  const float* fi = F + (size_t)i * DD + lane * 8;
  const float* fj = F + (size_t)j * DD + lane * 8;
  float4 a0 = *(const float4*)fi, a1 = *(const float4*)(fi + 4);
  float4 b0 = *(const float4*)fj, b1 = *(const float4*)(fj + 4);
  float d = a0.x*b0.x + a0.y*b0.y + a0.z*b0.z + a0.w*b0.w
          + a1.x*b1.x + a1.y*b1.y + a1.z*b1.z + a1.w*b1.w;
  #pragma unroll
  for (int o = 32; o; o >>= 1) d += __shfl_xor(d, o);
  if (lane == 0) {
    float d2 = sq[i] + sq[j] - 2.0f * d;
    nd[i] = sqrtf(fmaxf(d2, 1e-11f));
    atomicAdd(cnt, nc - 1);   // (nc-1) positive pairs for this anchor
  }
}

// -------- K3: fused triangular bf16 GEMM + hinge-loss reduction -----------
__global__ __launch_bounds__(256) void k_main(const u16* __restrict__ Fb,
    const float* __restrict__ sq, const int* __restrict__ labels,
    const float* __restrict__ nd, float* __restrict__ total) {
  const int bid = blockIdx.x;
  const int by = bid >> 6, bx = bid & 63;
  if (bx < by) return;                    // upper block-triangle only
  __shared__ __align__(16) u16 As[128 * 32];
  __shared__ __align__(16) u16 Bs[128 * 32];
  __shared__ float red[4];
  const int tid = threadIdx.x;
  const int wid = tid >> 6, lane = tid & 63;
  const int wr = wid >> 1, wc = wid & 1;

  f32x4 acc[4][4];
  #pragma unroll
  for (int m = 0; m < 4; ++m)
    #pragma unroll
    for (int n = 0; n < 4; ++n)
      #pragma unroll
      for (int q = 0; q < 4; ++q) acc[m][n][q] = 0.0f;

  // staging: round r, chunk ch=r*4+wid covers rows [ch*16, ch*16+16)
  // global source is pre-swizzled so linear LDS dest + swizzled read match
  const int srow = lane >> 2;
  const int scol = (((lane & 3) ^ ((lane >> 3) & 3)) * 8);
  const size_t gA0 = (size_t)(by * 128) * DD + scol;
  const size_t gB0 = (size_t)(bx * 128) * DD + scol;

  for (int k0 = 0; k0 < DD; k0 += 32) {
    if (k0) __syncthreads();
    #pragma unroll
    for (int r = 0; r < 2; ++r) {
      const int ch = r * 4 + wid;
      const int row = ch * 16 + srow;
      __builtin_amdgcn_global_load_lds(
          (const __attribute__((address_space(1))) void*)(Fb + gA0 + (size_t)row * DD + k0),
          (__attribute__((address_space(3))) void*)(&As[ch * 512]), 16, 0, 0);
      __builtin_amdgcn_global_load_lds(
          (const __attribute__((address_space(1))) void*)(Fb + gB0 + (size_t)row * DD + k0),
          (__attribute__((address_space(3))) void*)(&Bs[ch * 512]), 16, 0, 0);
    }
    __syncthreads();
    short8 af[4], bf[4];
    const int r16 = lane & 15;
    const int slot = ((lane >> 4) ^ ((r16 >> 1) & 3));  // inverse of write swizzle
    #pragma unroll
    for (int m = 0; m < 4; ++m) {
      const int row = wr * 64 + m * 16 + r16;
      af[m] = *(const short8*)&As[row * 32 + slot * 8];
    }
    #pragma unroll
    for (int n = 0; n < 4; ++n) {
      const int row = wc * 64 + n * 16 + r16;
      bf[n] = *(const short8*)&Bs[row * 32 + slot * 8];
    }
    #pragma unroll
    for (int m = 0; m < 4; ++m)
      #pragma unroll
      for (int n = 0; n < 4; ++n)
        acc[m][n] = __builtin_amdgcn_mfma_f32_16x16x32_bf16(af[m], bf[n], acc[m][n], 0, 0, 0);
  }

  // fused epilogue: dist -> hinge terms (both orientations for off-diag tiles)
  const bool offd = (bx != by);
  float lsum = 0.0f;
  const int ib = by * 128 + wr * 64;
  const int jb = bx * 128 + wc * 64;
  int jj[4], labj[4]; float sqj[4], ndj[4];
  #pragma unroll
  for (int n = 0; n < 4; ++n) {
    const int j = jb + n * 16 + (lane & 15);
    jj[n] = j; sqj[n] = sq[j]; ndj[n] = nd[j]; labj[n] = labels[j];
  }
  #pragma unroll
  for (int m = 0; m < 4; ++m) {
    #pragma unroll
    for (int q = 0; q < 4; ++q) {
      const int i = ib + m * 16 + (lane >> 4) * 4 + q;   // C/D layout: row=(lane>>4)*4+q
      const float sqi = sq[i];
      const float ndi = nd[i];
      const int labi = labels[i];
      #pragma unroll
      for (int n = 0; n < 4; ++n) {
        const float g = acc[m][n][q];
        const float dist = sqrtf(fmaxf(sqi + sqj[n] - 2.0f * g, 1e-11f));
        if ((labi == labj[n]) & (i != jj[n])) {
          float term = fmaxf(1.0f + dist - ndi, 0.0f);          // anchor i
          if (offd) term += fmaxf(1.0f + dist - ndj[n], 0.0f);  // mirrored anchor j
          lsum += term;
        }
      }
    }
  }
  #pragma unroll
  for (int o = 32; o; o >>= 1) lsum += __shfl_xor(lsum, o);
  if (lane == 0) red[wid] = lsum;
  __syncthreads();
  if (tid == 0) atomicAdd(total, red[0] + red[1] + red[2] + red[3]);
}

// ---------------- K4: final divide ----------------------------------------
__global__ void k_fin(const float* __restrict__ acc, float* __restrict__ out) {
  const float tot = acc[0];
  const int cnt = *(const int*)(acc + 1);
  out[0] = tot / (float)cnt;
}

extern "C" void kernel_launch(void* const* d_in, const int* in_sizes, int n_in,
                              void* d_out, int out_size, void* d_ws, size_t ws_size,
                              hipStream_t stream) {
  const float* F = (const float*)d_in[0];
  const int* labels = (const int*)d_in[1];   // harness materializes integers as int32
  const float* negu = (const float*)d_in[2];
  char* ws = (char*)d_ws;
  u16*   Fb    = (u16*)(ws + FB_OFF);
  float* sq    = (float*)(ws + SQ_OFF);
  float* nd    = (float*)(ws + ND_OFF);
  float* accf  = (float*)(ws + ACC_OFF);
  int*   cnt   = (int*)(ws + ACC_OFF + 4);
  int*   cc    = (int*)(ws + CC_OFF);

  hipMemsetAsync(ws + ACC_OFF, 0, 64 + 256 * 4, stream);
  k_prep<<<NN / 4, 256, 0, stream>>>(F, labels, Fb, sq, cc);
  k_neg <<<NN / 4, 256, 0, stream>>>(F, sq, labels, negu, cc, nd, cnt);
  k_main<<<64 * 64, 256, 0, stream>>>(Fb, sq, labels, nd, accf);
  k_fin <<<1, 1, 0, stream>>>(accf, (float*)d_out);
}

// Round 3
// 140.213 us; speedup vs baseline: 1.5121x; 1.5121x over previous
//
#include <hip/hip_runtime.h>
#include <hip/hip_bf16.h>
#include <cstdint>

#define NN 8192
#define DD 512
#define MAXC 256   // max members per class (avg 64, sigma 8 -> 256 is safe)

typedef unsigned short u16;
typedef __attribute__((ext_vector_type(8))) short short8;
typedef __attribute__((ext_vector_type(4))) float f32x4;

// workspace layout (bytes)
#define FB_OFF   ((size_t)0)                      // bf16 features: NN*DD*2 = 8 MB
#define SQ_OFF   (FB_OFF + (size_t)NN*DD*2)       // fp32 sq norms: NN*4
#define ND_OFF   (SQ_OFF + (size_t)NN*4)          // fp32 neg_dist: NN*4
#define ACC_OFF  (ND_OFF + (size_t)NN*4)          // total(float) @+0, cnt(int) @+4
#define CC_OFF   (ACC_OFF + 64)                   // class counts: 128*4
#define POS_OFF  (CC_OFF + 1024)                  // class member positions: 128*MAXC*4
#define NIX_OFF  (POS_OFF + (size_t)128*MAXC*4)   // negidx: NN*4

// ---------------- K1: sq norms + bf16 cast --------------------------------
__global__ __launch_bounds__(256) void k_prep(const float* __restrict__ F,
    u16* __restrict__ Fb, float* __restrict__ sq) {
  const int wid = threadIdx.x >> 6, lane = threadIdx.x & 63;
  const int row = blockIdx.x * 4 + wid;
  const float* fr = F + (size_t)row * DD + lane * 8;
  float4 v0 = *(const float4*)fr;
  float4 v1 = *(const float4*)(fr + 4);
  float s = v0.x*v0.x + v0.y*v0.y + v0.z*v0.z + v0.w*v0.w
          + v1.x*v1.x + v1.y*v1.y + v1.z*v1.z + v1.w*v1.w;
  #pragma unroll
  for (int o = 32; o; o >>= 1) s += __shfl_xor(s, o);
  float t[8] = {v0.x, v0.y, v0.z, v0.w, v1.x, v1.y, v1.z, v1.w};
  unsigned p[8];
  #pragma unroll
  for (int e = 0; e < 8; ++e) {   // RNE fp32->bf16
    unsigned b = __float_as_uint(t[e]);
    b += 0x7fffu + ((b >> 16) & 1u);
    p[e] = b >> 16;
  }
  uint4 w;
  w.x = p[0] | (p[1] << 16); w.y = p[2] | (p[3] << 16);
  w.z = p[4] | (p[5] << 16); w.w = p[6] | (p[7] << 16);
  *(uint4*)(Fb + (size_t)row * DD + lane * 8) = w;
  if (lane == 0) sq[row] = s;
}

// ------ K1b: per-class ordered member positions + counts (1 wave/class) ---
__global__ __launch_bounds__(64) void k_classpos(const int* __restrict__ labels,
    int* __restrict__ cc, int* __restrict__ pos) {
  const int c = blockIdx.x;
  const int lane = threadIdx.x;
  int running = 0;
  for (int base = 0; base < NN; base += 64) {
    const int lb = labels[base + lane];
    const unsigned long long m = __ballot(lb == c);
    if (lb == c) {
      const int before = __popcll(m & ((1ull << lane) - 1ull));
      pos[c * MAXC + running + before] = base + lane;
    }
    running += __popcll(m);
  }
  if (lane == 0) cc[c] = running;
}

// ------ K2a: k-th negative via class position list (1 thread/anchor) ------
__global__ __launch_bounds__(256) void k_selneg(const int* __restrict__ labels,
    const float* __restrict__ negu, const int* __restrict__ cc,
    const int* __restrict__ pos, int* __restrict__ negidx,
    int* __restrict__ cnt) {
  const int i = blockIdx.x * 256 + threadIdx.x;
  const int c = labels[i];
  const int nc = cc[c & 127];
  const int n_neg = NN - nc;
  int j = -1;
  if (n_neg > 0) {
    int k = (int)floorf(negu[i] * (float)n_neg);  // exact fp32 replica of reference
    k = k < 0 ? 0 : (k > n_neg - 1 ? n_neg - 1 : k);
    j = k;
    const int* pc = pos + (c & 127) * MAXC;
    for (int t = 0; t < nc; ++t) {                // predicated, loads pipeline
      const int p = pc[t];
      j += (p <= j);
    }
  }
  negidx[i] = j;
  int contrib = (n_neg > 0) ? (nc - 1) : 0;       // positive pairs for this anchor
  #pragma unroll
  for (int o = 32; o; o >>= 1) contrib += __shfl_xor(contrib, o);
  if ((threadIdx.x & 63) == 0) atomicAdd(cnt, contrib);
}

// ------------ K2b: fp32 neg_dist (1 wave/anchor) --------------------------
__global__ __launch_bounds__(256) void k_negdot(const float* __restrict__ F,
    const float* __restrict__ sq, const int* __restrict__ negidx,
    float* __restrict__ nd) {
  const int wid = threadIdx.x >> 6, lane = threadIdx.x & 63;
  const int i = blockIdx.x * 4 + wid;
  const int j = negidx[i];
  if (j < 0) { if (lane == 0) nd[i] = __builtin_inff(); return; }
  const float* fi = F + (size_t)i * DD + lane * 8;
  const float* fj = F + (size_t)j * DD + lane * 8;
  float4 a0 = *(const float4*)fi, a1 = *(const float4*)(fi + 4);
  float4 b0 = *(const float4*)fj, b1 = *(const float4*)(fj + 4);
  float d = a0.x*b0.x + a0.y*b0.y + a0.z*b0.z + a0.w*b0.w
          + a1.x*b1.x + a1.y*b1.y + a1.z*b1.z + a1.w*b1.w;
  #pragma unroll
  for (int o = 32; o; o >>= 1) d += __shfl_xor(d, o);
  if (lane == 0) {
    float d2 = sq[i] + sq[j] - 2.0f * d;
    nd[i] = sqrtf(fmaxf(d2, 1e-11f));
  }
}

// -------- K3: fused triangular bf16 GEMM + hinge-loss reduction -----------
__global__ __launch_bounds__(256) void k_main(const u16* __restrict__ Fb,
    const float* __restrict__ sq, const int* __restrict__ labels,
    const float* __restrict__ nd, float* __restrict__ total) {
  const int bid = blockIdx.x;
  const int by = bid >> 6, bx = bid & 63;
  if (bx < by) return;                    // upper block-triangle only
  __shared__ __align__(16) u16 As[128 * 32];
  __shared__ __align__(16) u16 Bs[128 * 32];
  __shared__ float red[4];
  const int tid = threadIdx.x;
  const int wid = tid >> 6, lane = tid & 63;
  const int wr = wid >> 1, wc = wid & 1;

  f32x4 acc[4][4];
  #pragma unroll
  for (int m = 0; m < 4; ++m)
    #pragma unroll
    for (int n = 0; n < 4; ++n)
      #pragma unroll
      for (int q = 0; q < 4; ++q) acc[m][n][q] = 0.0f;

  // staging: round r, chunk ch=r*4+wid covers rows [ch*16, ch*16+16)
  // global source is pre-swizzled so linear LDS dest + swizzled read match
  const int srow = lane >> 2;
  const int scol = (((lane & 3) ^ ((lane >> 3) & 3)) * 8);
  const size_t gA0 = (size_t)(by * 128) * DD + scol;
  const size_t gB0 = (size_t)(bx * 128) * DD + scol;

  for (int k0 = 0; k0 < DD; k0 += 32) {
    if (k0) __syncthreads();
    #pragma unroll
    for (int r = 0; r < 2; ++r) {
      const int ch = r * 4 + wid;
      const int row = ch * 16 + srow;
      __builtin_amdgcn_global_load_lds(
          (const __attribute__((address_space(1))) void*)(Fb + gA0 + (size_t)row * DD + k0),
          (__attribute__((address_space(3))) void*)(&As[ch * 512]), 16, 0, 0);
      __builtin_amdgcn_global_load_lds(
          (const __attribute__((address_space(1))) void*)(Fb + gB0 + (size_t)row * DD + k0),
          (__attribute__((address_space(3))) void*)(&Bs[ch * 512]), 16, 0, 0);
    }
    __syncthreads();
    short8 af[4], bf[4];
    const int r16 = lane & 15;
    const int slot = ((lane >> 4) ^ ((r16 >> 1) & 3));  // inverse of write swizzle
    #pragma unroll
    for (int m = 0; m < 4; ++m) {
      const int row = wr * 64 + m * 16 + r16;
      af[m] = *(const short8*)&As[row * 32 + slot * 8];
    }
    #pragma unroll
    for (int n = 0; n < 4; ++n) {
      const int row = wc * 64 + n * 16 + r16;
      bf[n] = *(const short8*)&Bs[row * 32 + slot * 8];
    }
    #pragma unroll
    for (int m = 0; m < 4; ++m)
      #pragma unroll
      for (int n = 0; n < 4; ++n)
        acc[m][n] = __builtin_amdgcn_mfma_f32_16x16x32_bf16(af[m], bf[n], acc[m][n], 0, 0, 0);
  }

  // fused epilogue: dist -> hinge terms (both orientations for off-diag tiles)
  const bool offd = (bx != by);
  float lsum = 0.0f;
  const int ib = by * 128 + wr * 64;
  const int jb = bx * 128 + wc * 64;
  int jj[4], labj[4]; float sqj[4], ndj[4];
  #pragma unroll
  for (int n = 0; n < 4; ++n) {
    const int j = jb + n * 16 + (lane & 15);
    jj[n] = j; sqj[n] = sq[j]; ndj[n] = nd[j]; labj[n] = labels[j];
  }
  #pragma unroll
  for (int m = 0; m < 4; ++m) {
    #pragma unroll
    for (int q = 0; q < 4; ++q) {
      const int i = ib + m * 16 + (lane >> 4) * 4 + q;   // C/D layout: row=(lane>>4)*4+q
      const float sqi = sq[i];
      const float ndi = nd[i];
      const int labi = labels[i];
      #pragma unroll
      for (int n = 0; n < 4; ++n) {
        const float g = acc[m][n][q];
        const float dist = sqrtf(fmaxf(sqi + sqj[n] - 2.0f * g, 1e-11f));
        if ((labi == labj[n]) & (i != jj[n])) {
          float term = fmaxf(1.0f + dist - ndi, 0.0f);          // anchor i
          if (offd) term += fmaxf(1.0f + dist - ndj[n], 0.0f);  // mirrored anchor j
          lsum += term;
        }
      }
    }
  }
  #pragma unroll
  for (int o = 32; o; o >>= 1) lsum += __shfl_xor(lsum, o);
  if (lane == 0) red[wid] = lsum;
  __syncthreads();
  if (tid == 0) atomicAdd(total, red[0] + red[1] + red[2] + red[3]);
}

// ---------------- K4: final divide ----------------------------------------
__global__ void k_fin(const float* __restrict__ acc, float* __restrict__ out) {
  const float tot = acc[0];
  const int cnt = *(const int*)(acc + 1);
  out[0] = tot / (float)cnt;
}

extern "C" void kernel_launch(void* const* d_in, const int* in_sizes, int n_in,
                              void* d_out, int out_size, void* d_ws, size_t ws_size,
                              hipStream_t stream) {
  const float* F = (const float*)d_in[0];
  const int* labels = (const int*)d_in[1];   // harness materializes integers as int32
  const float* negu = (const float*)d_in[2];
  char* ws = (char*)d_ws;
  u16*   Fb    = (u16*)(ws + FB_OFF);
  float* sq    = (float*)(ws + SQ_OFF);
  float* nd    = (float*)(ws + ND_OFF);
  float* accf  = (float*)(ws + ACC_OFF);
  int*   cnt   = (int*)(ws + ACC_OFF + 4);
  int*   cc    = (int*)(ws + CC_OFF);
  int*   pos   = (int*)(ws + POS_OFF);
  int*   nix   = (int*)(ws + NIX_OFF);

  hipMemsetAsync(ws + ACC_OFF, 0, 64, stream);
  k_prep    <<<NN / 4, 256, 0, stream>>>(F, Fb, sq);
  k_classpos<<<128,     64, 0, stream>>>(labels, cc, pos);
  k_selneg  <<<NN / 256, 256, 0, stream>>>(labels, negu, cc, pos, nix, cnt);
  k_negdot  <<<NN / 4, 256, 0, stream>>>(F, sq, nix, nd);
  k_main    <<<64 * 64, 256, 0, stream>>>(Fb, sq, labels, nd, accf);
  k_fin     <<<1, 1, 0, stream>>>(accf, (float*)d_out);
}

// Round 4
// 44.809 us; speedup vs baseline: 4.7314x; 3.1291x over previous
//
#include <hip/hip_runtime.h>
#include <hip/hip_bf16.h>
#include <cstdint>

#define NN 8192
#define DD 512
#define NC 128      // number of classes

typedef unsigned short u16;
typedef __attribute__((ext_vector_type(8))) short short8;
typedef __attribute__((ext_vector_type(4))) float f32x4;

#define AS1 __attribute__((address_space(1)))
#define AS3 __attribute__((address_space(3)))

// workspace layout (bytes)
#define FB_OFF   ((size_t)0)                      // bf16 features: NN*DD*2 = 8 MB
#define SQ_OFF   (FB_OFF + (size_t)NN*DD*2)       // fp32 sq norms: NN*4
#define ND_OFF   (SQ_OFF + (size_t)NN*4)          // fp32 neg_dist: NN*4
#define ACC_OFF  (ND_OFF + (size_t)NN*4)          // total(float) @+0, cnt(int) @+4
#define CC_OFF   (ACC_OFF + 64)                   // class counts: NC*4
#define POS_OFF  (CC_OFF + 1024)                  // ordered member positions: NC*128*4

// ---------------- K1: sq norms + bf16 cast --------------------------------
__global__ __launch_bounds__(256) void k_prep(const float* __restrict__ F,
    u16* __restrict__ Fb, float* __restrict__ sq) {
  const int wid = threadIdx.x >> 6, lane = threadIdx.x & 63;
  const int row = blockIdx.x * 4 + wid;
  const float* fr = F + (size_t)row * DD + lane * 8;
  float4 v0 = *(const float4*)fr;
  float4 v1 = *(const float4*)(fr + 4);
  float s = v0.x*v0.x + v0.y*v0.y + v0.z*v0.z + v0.w*v0.w
          + v1.x*v1.x + v1.y*v1.y + v1.z*v1.z + v1.w*v1.w;
  #pragma unroll
  for (int o = 32; o; o >>= 1) s += __shfl_xor(s, o);
  float t[8] = {v0.x, v0.y, v0.z, v0.w, v1.x, v1.y, v1.z, v1.w};
  unsigned p[8];
  #pragma unroll
  for (int e = 0; e < 8; ++e) {   // RNE fp32->bf16
    unsigned b = __float_as_uint(t[e]);
    b += 0x7fffu + ((b >> 16) & 1u);
    p[e] = b >> 16;
  }
  uint4 w;
  w.x = p[0] | (p[1] << 16); w.y = p[2] | (p[3] << 16);
  w.z = p[4] | (p[5] << 16); w.w = p[6] | (p[7] << 16);
  *(uint4*)(Fb + (size_t)row * DD + lane * 8) = w;
  if (lane == 0) sq[row] = s;
}

// ---- K1b: ordered member positions per class (4 waves, two-pass) ---------
// also accumulates the exact valid-pair count: sum_c nc*(nc-1)
__global__ __launch_bounds__(256) void k_classpos(const int* __restrict__ labels,
    int* __restrict__ cc, int* __restrict__ pos, int* __restrict__ cnt) {
  const int c = blockIdx.x;
  const int wid = threadIdx.x >> 6, lane = threadIdx.x & 63;
  __shared__ int wcnt[4], woff[4];
  const int base0 = wid * 2048;
  int cw = 0;
  for (int b = 0; b < 2048; b += 64)       // pass 1: count
    cw += __popcll(__ballot(labels[base0 + b + lane] == c));
  if (lane == 0) wcnt[wid] = cw;
  __syncthreads();
  if (threadIdx.x == 0) {
    int o = 0;
    #pragma unroll
    for (int w = 0; w < 4; ++w) { woff[w] = o; o += wcnt[w]; }
    cc[c] = o;
    if (o < NN) atomicAdd(cnt, o * (o - 1));
  }
  __syncthreads();
  int off = woff[wid];
  for (int b = 0; b < 2048; b += 64) {     // pass 2: emit (ascending order)
    const int idx = base0 + b + lane;
    const int hit = (labels[idx] == c);
    const unsigned long long m = __ballot(hit);
    if (hit) pos[c * 128 + off + __popcll(m & ((1ull << lane) - 1ull))] = idx;
    off += __popcll(m);
  }
  __syncthreads();
  const int nc = cc[c];
  for (int t = nc + threadIdx.x; t < 128; t += 256) pos[c * 128 + t] = 0; // pad
}

// ---- K2: fused k-th-negative (ballot rank) + fp32 neg_dist (1 wave/anchor)
__global__ __launch_bounds__(256) void k_neg2(const float* __restrict__ F,
    const float* __restrict__ sq, const int* __restrict__ labels,
    const float* __restrict__ negu, const int* __restrict__ cc,
    const int* __restrict__ pos, float* __restrict__ nd) {
  const int wid = threadIdx.x >> 6, lane = threadIdx.x & 63;
  const int i = blockIdx.x * 4 + wid;
  const int c = labels[i];
  const int nc = cc[c];
  const int n_neg = NN - nc;
  if (n_neg <= 0) { if (lane == 0) nd[i] = __builtin_inff(); return; }
  int k = (int)floorf(negu[i] * (float)n_neg);  // exact fp32 replica of reference
  k = k < 0 ? 0 : (k > n_neg - 1 ? n_neg - 1 : k);
  // rank: pos sorted ascending => pos[t]-t non-decreasing; t* = #{t: pos[t]-t <= k}
  const int* pc = pos + c * 128;
  const int p0 = pc[lane], p1 = pc[64 + lane];
  const int t = __popcll(__ballot((lane < nc) && (p0 - lane <= k)))
              + __popcll(__ballot((64 + lane < nc) && (p1 - (64 + lane) <= k)));
  const int j = k + t;
  // fp32 dot(f_i, f_j)
  const float* fi = F + (size_t)i * DD + lane * 8;
  const float* fj = F + (size_t)j * DD + lane * 8;
  float4 a0 = *(const float4*)fi, a1 = *(const float4*)(fi + 4);
  float4 b0 = *(const float4*)fj, b1 = *(const float4*)(fj + 4);
  float d = a0.x*b0.x + a0.y*b0.y + a0.z*b0.z + a0.w*b0.w
          + a1.x*b1.x + a1.y*b1.y + a1.z*b1.z + a1.w*b1.w;
  #pragma unroll
  for (int o = 32; o; o >>= 1) d += __shfl_xor(d, o);
  if (lane == 0) nd[i] = sqrtf(fmaxf(sq[i] + sq[j] - 2.0f * d, 1e-11f));
}

// ---- K3: per-class gathered Gram (<=128x128) + fused hinge reduction -----
// 4 waves (2x2), BK=64, double-buffered LDS, 2-phase pipeline, XOR swizzle.
__global__ __launch_bounds__(256) void k_cls(const u16* __restrict__ Fb,
    const float* __restrict__ sq, const float* __restrict__ nd,
    const int* __restrict__ cc, const int* __restrict__ pos,
    float* __restrict__ total) {
  const int c = blockIdx.x;
  __shared__ __align__(16) u16 P[2][128 * 64];   // 2 x 16 KB
  __shared__ int posc[128];
  __shared__ float red[4];
  const int tid = threadIdx.x, wid = tid >> 6, lane = tid & 63;
  const int nc = cc[c];
  if (tid < 128) posc[tid] = pos[c * 128 + tid];
  __syncthreads();
  if (nc < 2) return;                            // no positive pairs
  const int wr = wid >> 1, wc = wid & 1;
  const int r16 = lane & 15, gg = lane >> 4;

  // staging: wave wid covers stripes 4*wid..4*wid+3 (stripe = 8 rows x 128B)
  int grow[4];
  #pragma unroll
  for (int s = 0; s < 4; ++s) grow[s] = posc[wid * 32 + s * 8 + (lane >> 3)];
  const int swzg = (((lane & 7) ^ (lane >> 3)) << 4);   // swizzled 16B granule
  const char* fb = (const char*)Fb;

  f32x4 acc[4][4];
  #pragma unroll
  for (int m = 0; m < 4; ++m)
    #pragma unroll
    for (int n = 0; n < 4; ++n)
      #pragma unroll
      for (int q = 0; q < 4; ++q) acc[m][n][q] = 0.0f;

  #define STAGE(buf, kstep) do {                                              \
    const int kb_ = (kstep) * 128;                                            \
    _Pragma("unroll")                                                         \
    for (int s_ = 0; s_ < 4; ++s_)                                            \
      __builtin_amdgcn_global_load_lds(                                       \
        (const AS1 void*)(fb + (size_t)grow[s_] * 1024 + kb_ + swzg),         \
        (AS3 void*)(&P[buf][(wid * 32 + s_ * 8) * 64]), 16, 0, 0);            \
  } while (0)

  STAGE(0, 0);
  __syncthreads();
  for (int t = 0; t < 8; ++t) {
    if (t < 7) STAGE((t + 1) & 1, t + 1);
    const u16* p = P[t & 1];
    #pragma unroll
    for (int ks = 0; ks < 2; ++ks) {
      short8 af[4], bf[4];
      #pragma unroll
      for (int m = 0; m < 4; ++m) {
        const int row = wr * 64 + m * 16 + r16;
        const int gl = (ks * 4 + gg) ^ (row & 7);
        af[m] = *(const short8*)&p[row * 64 + gl * 8];
      }
      #pragma unroll
      for (int n = 0; n < 4; ++n) {
        const int row = wc * 64 + n * 16 + r16;
        const int gl = (ks * 4 + gg) ^ (row & 7);
        bf[n] = *(const short8*)&p[row * 64 + gl * 8];
      }
      #pragma unroll
      for (int m = 0; m < 4; ++m)
        #pragma unroll
        for (int n = 0; n < 4; ++n)
          acc[m][n] = __builtin_amdgcn_mfma_f32_16x16x32_bf16(af[m], bf[n], acc[m][n], 0, 0, 0);
    }
    __syncthreads();
  }

  // epilogue: hinge over valid (mi != nj, both < nc) ordered pairs
  float lsum = 0.0f;
  int njv[4], jv[4]; float sqj[4];
  #pragma unroll
  for (int n = 0; n < 4; ++n) {
    const int nj = wc * 64 + n * 16 + r16;
    njv[n] = nj; jv[n] = posc[nj]; sqj[n] = sq[jv[n]];
  }
  #pragma unroll
  for (int m = 0; m < 4; ++m) {
    #pragma unroll
    for (int q = 0; q < 4; ++q) {
      const int mi = wr * 64 + m * 16 + gg * 4 + q;   // C/D: row=(lane>>4)*4+q
      const int i = posc[mi];
      const float sqi = sq[i], ndi = nd[i];
      const bool vi = mi < nc;
      #pragma unroll
      for (int n = 0; n < 4; ++n) {
        const float g = acc[m][n][q];
        const float dist = sqrtf(fmaxf(sqi + sqj[n] - 2.0f * g, 1e-11f));
        if (vi & (njv[n] < nc) & (mi != njv[n]))
          lsum += fmaxf(1.0f + dist - ndi, 0.0f);     // nd=inf -> 0 automatically
      }
    }
  }
  #pragma unroll
  for (int o = 32; o; o >>= 1) lsum += __shfl_xor(lsum, o);
  if (lane == 0) red[wid] = lsum;
  __syncthreads();
  if (tid == 0) atomicAdd(total, red[0] + red[1] + red[2] + red[3]);
}

// ---------------- K4: final divide ----------------------------------------
__global__ void k_fin(const float* __restrict__ acc, float* __restrict__ out) {
  const float tot = acc[0];
  const int cnt = *(const int*)(acc + 1);
  out[0] = tot / (float)cnt;
}

extern "C" void kernel_launch(void* const* d_in, const int* in_sizes, int n_in,
                              void* d_out, int out_size, void* d_ws, size_t ws_size,
                              hipStream_t stream) {
  const float* F = (const float*)d_in[0];
  const int* labels = (const int*)d_in[1];   // harness materializes integers as int32
  const float* negu = (const float*)d_in[2];
  char* ws = (char*)d_ws;
  u16*   Fb    = (u16*)(ws + FB_OFF);
  float* sq    = (float*)(ws + SQ_OFF);
  float* nd    = (float*)(ws + ND_OFF);
  float* accf  = (float*)(ws + ACC_OFF);
  int*   cnt   = (int*)(ws + ACC_OFF + 4);
  int*   cc    = (int*)(ws + CC_OFF);
  int*   pos   = (int*)(ws + POS_OFF);

  hipMemsetAsync(ws + ACC_OFF, 0, 64, stream);
  k_prep    <<<NN / 4, 256, 0, stream>>>(F, Fb, sq);
  k_classpos<<<NC,    256, 0, stream>>>(labels, cc, pos, cnt);
  k_neg2    <<<NN / 4, 256, 0, stream>>>(F, sq, labels, negu, cc, pos, nd);
  k_cls     <<<NC,    256, 0, stream>>>(Fb, sq, nd, cc, pos, accf);
  k_fin     <<<1, 1, 0, stream>>>(accf, (float*)d_out);
}

// Round 5
// 40.100 us; speedup vs baseline: 5.2870x; 1.1174x over previous
//
#include <hip/hip_runtime.h>
#include <hip/hip_bf16.h>
#include <cstdint>

#define NN 8192
#define DD 512
#define NC 128      // number of classes

typedef unsigned short u16;
typedef __attribute__((ext_vector_type(8))) short short8;
typedef __attribute__((ext_vector_type(4))) float f32x4;

#define AS1 __attribute__((address_space(1)))
#define AS3 __attribute__((address_space(3)))

// workspace layout (bytes)
#define FB_OFF   ((size_t)0)                      // bf16 features: NN*DD*2 = 8 MB
#define SQ_OFF   (FB_OFF + (size_t)NN*DD*2)       // fp32 sq norms: NN*4
#define ND_OFF   (SQ_OFF + (size_t)NN*4)          // fp32 neg_dist: NN*4
#define ACC_OFF  (ND_OFF + (size_t)NN*4)          // total(f32)@+0, cnt(int)@+4, done(int)@+8
#define CC_OFF   (ACC_OFF + 64)                   // class counts: NC*4
#define POS_OFF  (CC_OFF + 1024)                  // ordered member positions: NC*128*4

// ---------------- K1: sq norms + bf16 cast + zero accumulators ------------
__global__ __launch_bounds__(256) void k_prep(const float* __restrict__ F,
    u16* __restrict__ Fb, float* __restrict__ sq, int* __restrict__ accz) {
  if (blockIdx.x == 0 && threadIdx.x < 16) accz[threadIdx.x] = 0;  // total,cnt,done
  const int wid = threadIdx.x >> 6, lane = threadIdx.x & 63;
  const int row = blockIdx.x * 4 + wid;
  const float* fr = F + (size_t)row * DD + lane * 8;
  float4 v0 = *(const float4*)fr;
  float4 v1 = *(const float4*)(fr + 4);
  float s = v0.x*v0.x + v0.y*v0.y + v0.z*v0.z + v0.w*v0.w
          + v1.x*v1.x + v1.y*v1.y + v1.z*v1.z + v1.w*v1.w;
  #pragma unroll
  for (int o = 32; o; o >>= 1) s += __shfl_xor(s, o);
  float t[8] = {v0.x, v0.y, v0.z, v0.w, v1.x, v1.y, v1.z, v1.w};
  unsigned p[8];
  #pragma unroll
  for (int e = 0; e < 8; ++e) {   // RNE fp32->bf16
    unsigned b = __float_as_uint(t[e]);
    b += 0x7fffu + ((b >> 16) & 1u);
    p[e] = b >> 16;
  }
  uint4 w;
  w.x = p[0] | (p[1] << 16); w.y = p[2] | (p[3] << 16);
  w.z = p[4] | (p[5] << 16); w.w = p[6] | (p[7] << 16);
  *(uint4*)(Fb + (size_t)row * DD + lane * 8) = w;
  if (lane == 0) sq[row] = s;
}

// ---- K1b: ordered member positions per class (4 waves, two-pass) ---------
// also accumulates the exact valid-pair count: sum_c nc*(nc-1)
__global__ __launch_bounds__(256) void k_classpos(const int* __restrict__ labels,
    int* __restrict__ cc, int* __restrict__ pos, int* __restrict__ cnt) {
  const int c = blockIdx.x;
  const int wid = threadIdx.x >> 6, lane = threadIdx.x & 63;
  __shared__ int wcnt[4], woff[4];
  const int base0 = wid * 2048;
  int cw = 0;
  for (int b = 0; b < 2048; b += 64)       // pass 1: count
    cw += __popcll(__ballot(labels[base0 + b + lane] == c));
  if (lane == 0) wcnt[wid] = cw;
  __syncthreads();
  if (threadIdx.x == 0) {
    int o = 0;
    #pragma unroll
    for (int w = 0; w < 4; ++w) { woff[w] = o; o += wcnt[w]; }
    cc[c] = o;
    if (o < NN) atomicAdd(cnt, o * (o - 1));
  }
  __syncthreads();
  int off = woff[wid];
  for (int b = 0; b < 2048; b += 64) {     // pass 2: emit (ascending order)
    const int idx = base0 + b + lane;
    const int hit = (labels[idx] == c);
    const unsigned long long m = __ballot(hit);
    if (hit) pos[c * 128 + off + __popcll(m & ((1ull << lane) - 1ull))] = idx;
    off += __popcll(m);
  }
  __syncthreads();
  const int nc = cc[c];
  for (int t = nc + threadIdx.x; t < 128; t += 256) pos[c * 128 + t] = 0; // pad
}

// ---- K2: fused k-th-negative (ballot rank) + fp32 neg_dist (1 wave/anchor)
__global__ __launch_bounds__(256) void k_neg2(const float* __restrict__ F,
    const float* __restrict__ sq, const int* __restrict__ labels,
    const float* __restrict__ negu, const int* __restrict__ cc,
    const int* __restrict__ pos, float* __restrict__ nd) {
  const int wid = threadIdx.x >> 6, lane = threadIdx.x & 63;
  const int i = blockIdx.x * 4 + wid;
  const int c = labels[i];
  const int nc = cc[c];
  const int n_neg = NN - nc;
  if (n_neg <= 0) { if (lane == 0) nd[i] = __builtin_inff(); return; }
  int k = (int)floorf(negu[i] * (float)n_neg);  // exact fp32 replica of reference
  k = k < 0 ? 0 : (k > n_neg - 1 ? n_neg - 1 : k);
  // rank: pos sorted ascending => pos[t]-t non-decreasing; t* = #{t: pos[t]-t <= k}
  const int* pc = pos + c * 128;
  const int p0 = pc[lane], p1 = pc[64 + lane];
  const int t = __popcll(__ballot((lane < nc) && (p0 - lane <= k)))
              + __popcll(__ballot((64 + lane < nc) && (p1 - (64 + lane) <= k)));
  const int j = k + t;
  // fp32 dot(f_i, f_j)
  const float* fi = F + (size_t)i * DD + lane * 8;
  const float* fj = F + (size_t)j * DD + lane * 8;
  float4 a0 = *(const float4*)fi, a1 = *(const float4*)(fi + 4);
  float4 b0 = *(const float4*)fj, b1 = *(const float4*)(fj + 4);
  float d = a0.x*b0.x + a0.y*b0.y + a0.z*b0.z + a0.w*b0.w
          + a1.x*b1.x + a1.y*b1.y + a1.z*b1.z + a1.w*b1.w;
  #pragma unroll
  for (int o = 32; o; o >>= 1) d += __shfl_xor(d, o);
  if (lane == 0) nd[i] = sqrtf(fmaxf(sq[i] + sq[j] - 2.0f * d, 1e-11f));
}

// ---- K3: per-class gathered Gram (<=128x128) + fused hinge reduction -----
// 4 waves (2x2), BK=64, double-buffered LDS, 2-phase pipeline, XOR swizzle.
// Last block finalizes: out = total / cnt  (device-scope atomics + fence).
__global__ __launch_bounds__(256) void k_cls(const u16* __restrict__ Fb,
    const float* __restrict__ sq, const float* __restrict__ nd,
    const int* __restrict__ cc, const int* __restrict__ pos,
    float* __restrict__ accf, float* __restrict__ out) {
  const int c = blockIdx.x;
  __shared__ __align__(16) u16 P[2][128 * 64];   // 2 x 16 KB
  __shared__ int posc[128];
  __shared__ float red[4];
  const int tid = threadIdx.x, wid = tid >> 6, lane = tid & 63;
  const int nc = cc[c];
  if (tid < 128) posc[tid] = pos[c * 128 + tid];
  __syncthreads();
  if (nc >= 2) {                                 // uniform branch per block
    const int wr = wid >> 1, wc = wid & 1;
    const int r16 = lane & 15, gg = lane >> 4;

    // staging: wave wid covers stripes 4*wid..4*wid+3 (stripe = 8 rows x 128B)
    int grow[4];
    #pragma unroll
    for (int s = 0; s < 4; ++s) grow[s] = posc[wid * 32 + s * 8 + (lane >> 3)];
    const int swzg = (((lane & 7) ^ (lane >> 3)) << 4);   // swizzled 16B granule
    const char* fb = (const char*)Fb;

    f32x4 acc[4][4];
    #pragma unroll
    for (int m = 0; m < 4; ++m)
      #pragma unroll
      for (int n = 0; n < 4; ++n)
        #pragma unroll
        for (int q = 0; q < 4; ++q) acc[m][n][q] = 0.0f;

    #define STAGE(buf, kstep) do {                                            \
      const int kb_ = (kstep) * 128;                                          \
      _Pragma("unroll")                                                       \
      for (int s_ = 0; s_ < 4; ++s_)                                          \
        __builtin_amdgcn_global_load_lds(                                     \
          (const AS1 void*)(fb + (size_t)grow[s_] * 1024 + kb_ + swzg),       \
          (AS3 void*)(&P[buf][(wid * 32 + s_ * 8) * 64]), 16, 0, 0);          \
    } while (0)

    STAGE(0, 0);
    __syncthreads();
    for (int t = 0; t < 8; ++t) {
      if (t < 7) STAGE((t + 1) & 1, t + 1);
      const u16* p = P[t & 1];
      #pragma unroll
      for (int ks = 0; ks < 2; ++ks) {
        short8 af[4], bf[4];
        #pragma unroll
        for (int m = 0; m < 4; ++m) {
          const int row = wr * 64 + m * 16 + r16;
          const int gl = (ks * 4 + gg) ^ (row & 7);
          af[m] = *(const short8*)&p[row * 64 + gl * 8];
        }
        #pragma unroll
        for (int n = 0; n < 4; ++n) {
          const int row = wc * 64 + n * 16 + r16;
          const int gl = (ks * 4 + gg) ^ (row & 7);
          bf[n] = *(const short8*)&p[row * 64 + gl * 8];
        }
        #pragma unroll
        for (int m = 0; m < 4; ++m)
          #pragma unroll
          for (int n = 0; n < 4; ++n)
            acc[m][n] = __builtin_amdgcn_mfma_f32_16x16x32_bf16(af[m], bf[n], acc[m][n], 0, 0, 0);
      }
      __syncthreads();
    }

    // epilogue: hinge over valid (mi != nj, both < nc) ordered pairs
    float lsum = 0.0f;
    int njv[4], jv[4]; float sqj[4];
    #pragma unroll
    for (int n = 0; n < 4; ++n) {
      const int nj = wc * 64 + n * 16 + r16;
      njv[n] = nj; jv[n] = posc[nj]; sqj[n] = sq[jv[n]];
    }
    #pragma unroll
    for (int m = 0; m < 4; ++m) {
      #pragma unroll
      for (int q = 0; q < 4; ++q) {
        const int mi = wr * 64 + m * 16 + gg * 4 + q;   // C/D: row=(lane>>4)*4+q
        const int i = posc[mi];
        const float sqi = sq[i], ndi = nd[i];
        const bool vi = mi < nc;
        #pragma unroll
        for (int n = 0; n < 4; ++n) {
          const float g = acc[m][n][q];
          const float dist = sqrtf(fmaxf(sqi + sqj[n] - 2.0f * g, 1e-11f));
          if (vi & (njv[n] < nc) & (mi != njv[n]))
            lsum += fmaxf(1.0f + dist - ndi, 0.0f);     // nd=inf -> 0 automatically
        }
      }
    }
    #pragma unroll
    for (int o = 32; o; o >>= 1) lsum += __shfl_xor(lsum, o);
    if (lane == 0) red[wid] = lsum;
    __syncthreads();
    if (tid == 0) atomicAdd(accf, red[0] + red[1] + red[2] + red[3]);
  }
  // last-block finalize
  if (tid == 0) {
    __threadfence();
    int* done = (int*)accf + 2;
    if (atomicAdd(done, 1) == NC - 1) {
      const float tot = atomicAdd(accf, 0.0f);          // atomic read
      const int n = *(volatile int*)((int*)accf + 1);   // written by k_classpos
      out[0] = tot / (float)n;
    }
  }
}

extern "C" void kernel_launch(void* const* d_in, const int* in_sizes, int n_in,
                              void* d_out, int out_size, void* d_ws, size_t ws_size,
                              hipStream_t stream) {
  const float* F = (const float*)d_in[0];
  const int* labels = (const int*)d_in[1];   // harness materializes integers as int32
  const float* negu = (const float*)d_in[2];
  char* ws = (char*)d_ws;
  u16*   Fb    = (u16*)(ws + FB_OFF);
  float* sq    = (float*)(ws + SQ_OFF);
  float* nd    = (float*)(ws + ND_OFF);
  float* accf  = (float*)(ws + ACC_OFF);
  int*   cnt   = (int*)(ws + ACC_OFF + 4);
  int*   cc    = (int*)(ws + CC_OFF);
  int*   pos   = (int*)(ws + POS_OFF);

  k_prep    <<<NN / 4, 256, 0, stream>>>(F, Fb, sq, (int*)accf);
  k_classpos<<<NC,    256, 0, stream>>>(labels, cc, pos, cnt);
  k_neg2    <<<NN / 4, 256, 0, stream>>>(F, sq, labels, negu, cc, pos, nd);
  k_cls     <<<NC,    256, 0, stream>>>(Fb, sq, nd, cc, pos, accf, (float*)d_out);
}

// Round 6
// 35.549 us; speedup vs baseline: 5.9638x; 1.1280x over previous
//
#include <hip/hip_runtime.h>
#include <hip/hip_bf16.h>
#include <cstdint>

#define NN 8192
#define DD 512
#define NC 128      // number of classes

typedef unsigned short u16;
typedef __attribute__((ext_vector_type(8))) short short8;
typedef __attribute__((ext_vector_type(4))) float f32x4;

#define AS1 __attribute__((address_space(1)))
#define AS3 __attribute__((address_space(3)))

// workspace layout (bytes)
#define FB_OFF   ((size_t)0)                      // bf16 features: NN*DD*2 = 8 MB
#define SQ_OFF   (FB_OFF + (size_t)NN*DD*2)       // fp32 sq norms: NN*4
#define ND_OFF   (SQ_OFF + (size_t)NN*4)          // fp32 neg_dist: NN*4
#define ACC_OFF  (ND_OFF + (size_t)NN*4)          // total(f32)@+0, cnt(int)@+4, done(int)@+8
#define CC_OFF   (ACC_OFF + 64)                   // class counts: NC*4
#define POS_OFF  (CC_OFF + 1024)                  // ordered member positions: NC*128*4

// ---- K1: fused {sq norms + bf16 cast + acc zero} | {per-class positions} --
// blocks 0..2047: prep (reads F only). blocks 2048..2175: classpos (labels
// only). The two halves are data-independent -> they overlap in one dispatch.
__global__ __launch_bounds__(256) void k_pc(const float* __restrict__ F,
    const int* __restrict__ labels, u16* __restrict__ Fb,
    float* __restrict__ sq, int* __restrict__ cc, int* __restrict__ pos,
    int* __restrict__ cnt, int* __restrict__ accz) {
  const int wid = threadIdx.x >> 6, lane = threadIdx.x & 63;
  if (blockIdx.x < 2048) {               // ---------------- prep half
    if (blockIdx.x == 0 && threadIdx.x < 16) accz[threadIdx.x] = 0;
    const int row = blockIdx.x * 4 + wid;
    const float* fr = F + (size_t)row * DD + lane * 8;
    float4 v0 = *(const float4*)fr;
    float4 v1 = *(const float4*)(fr + 4);
    float s = v0.x*v0.x + v0.y*v0.y + v0.z*v0.z + v0.w*v0.w
            + v1.x*v1.x + v1.y*v1.y + v1.z*v1.z + v1.w*v1.w;
    #pragma unroll
    for (int o = 32; o; o >>= 1) s += __shfl_xor(s, o);
    float t[8] = {v0.x, v0.y, v0.z, v0.w, v1.x, v1.y, v1.z, v1.w};
    unsigned p[8];
    #pragma unroll
    for (int e = 0; e < 8; ++e) {   // RNE fp32->bf16
      unsigned b = __float_as_uint(t[e]);
      b += 0x7fffu + ((b >> 16) & 1u);
      p[e] = b >> 16;
    }
    uint4 w;
    w.x = p[0] | (p[1] << 16); w.y = p[2] | (p[3] << 16);
    w.z = p[4] | (p[5] << 16); w.w = p[6] | (p[7] << 16);
    *(uint4*)(Fb + (size_t)row * DD + lane * 8) = w;
    if (lane == 0) sq[row] = s;
  } else {                               // ---------------- classpos half
    const int c = blockIdx.x - 2048;
    __shared__ int wcnt[4], woff[4];
    const int base0 = wid * 2048;
    int cw = 0;
    for (int b = 0; b < 2048; b += 64)   // pass 1: count
      cw += __popcll(__ballot(labels[base0 + b + lane] == c));
    if (lane == 0) wcnt[wid] = cw;
    __syncthreads();
    if (threadIdx.x == 0) {
      int o = 0;
      #pragma unroll
      for (int w = 0; w < 4; ++w) { woff[w] = o; o += wcnt[w]; }
      cc[c] = o;
      if (o < NN) atomicAdd(cnt, o * (o - 1));
    }
    __syncthreads();
    int off = woff[wid];
    for (int b = 0; b < 2048; b += 64) { // pass 2: emit (ascending order)
      const int idx = base0 + b + lane;
      const int hit = (labels[idx] == c);
      const unsigned long long m = __ballot(hit);
      if (hit) pos[c * 128 + off + __popcll(m & ((1ull << lane) - 1ull))] = idx;
      off += __popcll(m);
    }
    __syncthreads();
    const int nc = cc[c];
    for (int t = nc + threadIdx.x; t < 128; t += 256) pos[c * 128 + t] = 0;
  }
}

// ---- K2: fused k-th-negative (ballot rank) + fp32 neg_dist (1 wave/anchor)
__global__ __launch_bounds__(256) void k_neg2(const float* __restrict__ F,
    const float* __restrict__ sq, const int* __restrict__ labels,
    const float* __restrict__ negu, const int* __restrict__ cc,
    const int* __restrict__ pos, float* __restrict__ nd) {
  const int wid = threadIdx.x >> 6, lane = threadIdx.x & 63;
  const int i = blockIdx.x * 4 + wid;
  const int c = labels[i];
  const int nc = cc[c];
  const int n_neg = NN - nc;
  if (n_neg <= 0) { if (lane == 0) nd[i] = __builtin_inff(); return; }
  int k = (int)floorf(negu[i] * (float)n_neg);  // exact fp32 replica of reference
  k = k < 0 ? 0 : (k > n_neg - 1 ? n_neg - 1 : k);
  // rank: pos sorted ascending => pos[t]-t non-decreasing; t* = #{t: pos[t]-t <= k}
  const int* pc = pos + c * 128;
  const int p0 = pc[lane], p1 = pc[64 + lane];
  const int t = __popcll(__ballot((lane < nc) && (p0 - lane <= k)))
              + __popcll(__ballot((64 + lane < nc) && (p1 - (64 + lane) <= k)));
  const int j = k + t;
  // fp32 dot(f_i, f_j)
  const float* fi = F + (size_t)i * DD + lane * 8;
  const float* fj = F + (size_t)j * DD + lane * 8;
  float4 a0 = *(const float4*)fi, a1 = *(const float4*)(fi + 4);
  float4 b0 = *(const float4*)fj, b1 = *(const float4*)(fj + 4);
  float d = a0.x*b0.x + a0.y*b0.y + a0.z*b0.z + a0.w*b0.w
          + a1.x*b1.x + a1.y*b1.y + a1.z*b1.z + a1.w*b1.w;
  #pragma unroll
  for (int o = 32; o; o >>= 1) d += __shfl_xor(d, o);
  if (lane == 0) nd[i] = sqrtf(fmaxf(sq[i] + sq[j] - 2.0f * d, 1e-11f));
}

// ---- K3: per-class gathered Gram (<=128x128) + fused hinge reduction -----
// Whole 128x512 class tile staged to LDS (128 KB) in ONE shot: 32
// global_load_lds per wave, single barrier, then 256 MFMAs/wave from LDS.
// Swizzle: LDS granule x of row r holds global granule x^(r&7) (attn recipe).
__global__ __launch_bounds__(256) void k_cls(const u16* __restrict__ Fb,
    const float* __restrict__ sq, const float* __restrict__ nd,
    const int* __restrict__ cc, const int* __restrict__ pos,
    float* __restrict__ accf, float* __restrict__ out) {
  const int c = blockIdx.x;
  __shared__ __align__(16) u16 P[128 * 512];     // 128 KB: full class tile
  __shared__ int posc[128];
  __shared__ float red[4];
  const int tid = threadIdx.x, wid = tid >> 6, lane = tid & 63;
  const int nc = cc[c];
  if (tid < 128) posc[tid] = pos[c * 128 + tid];
  __syncthreads();
  if (nc >= 2) {                                 // uniform branch per block
    const int wr = wid >> 1, wc = wid & 1;
    const int r16 = lane & 15, gg = lane >> 4;
    const char* fb = (const char*)Fb;

    // stage: wave wid covers rows wid*32..wid*32+31; one instr = one row
    // (64 lanes x 16B = 1024B). lane l -> LDS granule l, global granule l^(s&7).
    #pragma unroll 8
    for (int s = 0; s < 32; ++s) {
      const int row = wid * 32 + s;
      const int gr = posc[row];
      __builtin_amdgcn_global_load_lds(
          (const AS1 void*)(fb + (size_t)gr * 1024 + ((lane ^ (s & 7)) << 4)),
          (AS3 void*)(&P[row * 512]), 16, 0, 0);
    }

    f32x4 acc[4][4];
    #pragma unroll
    for (int m = 0; m < 4; ++m)
      #pragma unroll
      for (int n = 0; n < 4; ++n)
        #pragma unroll
        for (int q = 0; q < 4; ++q) acc[m][n][q] = 0.0f;

    __syncthreads();                             // one vmcnt(0) drain total
    #pragma unroll 4
    for (int t = 0; t < 16; ++t) {               // K = 16 x 32
      short8 af[4], bf[4];
      #pragma unroll
      for (int m = 0; m < 4; ++m) {
        const int row = wr * 64 + m * 16 + r16;
        const int gl = (t * 4 + gg) ^ (row & 7);
        af[m] = *(const short8*)&P[row * 512 + gl * 8];
      }
      #pragma unroll
      for (int n = 0; n < 4; ++n) {
        const int row = wc * 64 + n * 16 + r16;
        const int gl = (t * 4 + gg) ^ (row & 7);
        bf[n] = *(const short8*)&P[row * 512 + gl * 8];
      }
      #pragma unroll
      for (int m = 0; m < 4; ++m)
        #pragma unroll
        for (int n = 0; n < 4; ++n)
          acc[m][n] = __builtin_amdgcn_mfma_f32_16x16x32_bf16(af[m], bf[n], acc[m][n], 0, 0, 0);
    }

    // epilogue: hinge over valid (mi != nj, both < nc) ordered pairs
    float lsum = 0.0f;
    int njv[4], jv[4]; float sqj[4];
    #pragma unroll
    for (int n = 0; n < 4; ++n) {
      const int nj = wc * 64 + n * 16 + r16;
      njv[n] = nj; jv[n] = posc[nj]; sqj[n] = sq[jv[n]];
    }
    #pragma unroll
    for (int m = 0; m < 4; ++m) {
      #pragma unroll
      for (int q = 0; q < 4; ++q) {
        const int mi = wr * 64 + m * 16 + gg * 4 + q;   // C/D: row=(lane>>4)*4+q
        const int i = posc[mi];
        const float sqi = sq[i], ndi = nd[i];
        const bool vi = mi < nc;
        #pragma unroll
        for (int n = 0; n < 4; ++n) {
          const float g = acc[m][n][q];
          const float dist = sqrtf(fmaxf(sqi + sqj[n] - 2.0f * g, 1e-11f));
          if (vi & (njv[n] < nc) & (mi != njv[n]))
            lsum += fmaxf(1.0f + dist - ndi, 0.0f);     // nd=inf -> 0 automatically
        }
      }
    }
    #pragma unroll
    for (int o = 32; o; o >>= 1) lsum += __shfl_xor(lsum, o);
    if (lane == 0) red[wid] = lsum;
    __syncthreads();
    if (tid == 0) atomicAdd(accf, red[0] + red[1] + red[2] + red[3]);
  }
  // last-block finalize
  if (tid == 0) {
    __threadfence();
    int* done = (int*)accf + 2;
    if (atomicAdd(done, 1) == NC - 1) {
      const float tot = atomicAdd(accf, 0.0f);          // atomic read
      const int n = *(volatile int*)((int*)accf + 1);   // written by k_pc
      out[0] = tot / (float)n;
    }
  }
}

extern "C" void kernel_launch(void* const* d_in, const int* in_sizes, int n_in,
                              void* d_out, int out_size, void* d_ws, size_t ws_size,
                              hipStream_t stream) {
  const float* F = (const float*)d_in[0];
  const int* labels = (const int*)d_in[1];   // harness materializes integers as int32
  const float* negu = (const float*)d_in[2];
  char* ws = (char*)d_ws;
  u16*   Fb    = (u16*)(ws + FB_OFF);
  float* sq    = (float*)(ws + SQ_OFF);
  float* nd    = (float*)(ws + ND_OFF);
  float* accf  = (float*)(ws + ACC_OFF);
  int*   cnt   = (int*)(ws + ACC_OFF + 4);
  int*   cc    = (int*)(ws + CC_OFF);
  int*   pos   = (int*)(ws + POS_OFF);

  k_pc  <<<2048 + NC, 256, 0, stream>>>(F, labels, Fb, sq, cc, pos, cnt, (int*)accf);
  k_neg2<<<NN / 4,    256, 0, stream>>>(F, sq, labels, negu, cc, pos, nd);
  k_cls <<<NC,        256, 0, stream>>>(Fb, sq, nd, cc, pos, accf, (float*)d_out);
}